// Round 1
// baseline (149.454 us; speedup 1.0000x reference)
//
#include <hip/hip_runtime.h>

static constexpr int C  = 512;
static constexpr int P  = 4096;    // H*W

typedef _Float16 half8  __attribute__((ext_vector_type(8)));
typedef _Float16 half2v __attribute__((ext_vector_type(2)));
typedef float    f32x4  __attribute__((ext_vector_type(4)));

__device__ __forceinline__ int refl(int q) { return q < 0 ? 1 : (q > 63 ? 62 : q); }

__device__ __forceinline__ void g2l16(const void* g, const void* l) {
    __builtin_amdgcn_global_load_lds((const __attribute__((address_space(1))) unsigned int*)g,
                                     (__attribute__((address_space(3))) unsigned int*)l, 16, 0, 0);
}

// ---------------- transpose fp32 [c][p] -> fp16 [p][c]; per-cblk style sq-norm partials ----------------
__global__ __launch_bounds__(256) void k_prep(const float* __restrict__ content, const float* __restrict__ style,
                                              _Float16* __restrict__ Ah, _Float16* __restrict__ Bh,
                                              float* __restrict__ sqn_part) {
    __shared__ float T[64][65];
    __shared__ float R4[4][64];
    const int p0 = (blockIdx.x & 63) * 64, c0 = (blockIdx.x >> 6) * 64;
    const int pl = threadIdx.x & 63, cq = threadIdx.x >> 6;   // read role
    const int pv = threadIdx.x >> 3;                           // write role: p row 0..31 (+32)
    const int cv = (threadIdx.x & 7) * 8;                      // write role: c base

    // content
    #pragma unroll
    for (int r = 0; r < 16; ++r)
        T[cq + r * 4][pl] = content[(size_t)(c0 + cq + r * 4) * P + p0 + pl];
    __syncthreads();
    #pragma unroll
    for (int r = 0; r < 2; ++r) {
        int pl2 = pv + r * 32;
        half8 v;
        #pragma unroll
        for (int u = 0; u < 8; ++u) v[u] = (_Float16)T[cv + u][pl2];
        *(half8*)(Ah + (size_t)(p0 + pl2) * C + c0 + cv) = v;
    }
    __syncthreads();

    // style
    float sq = 0.f;
    #pragma unroll
    for (int r = 0; r < 16; ++r) {
        float v = style[(size_t)(c0 + cq + r * 4) * P + p0 + pl];
        T[cq + r * 4][pl] = v;
        sq += v * v;
    }
    R4[cq][pl] = sq;
    __syncthreads();
    if (cq == 0)
        sqn_part[(size_t)(blockIdx.x >> 6) * P + p0 + pl] = R4[0][pl] + R4[1][pl] + R4[2][pl] + R4[3][pl];
    #pragma unroll
    for (int r = 0; r < 2; ++r) {
        int pl2 = pv + r * 32;
        half8 v;
        #pragma unroll
        for (int u = 0; u < 8; ++u) v[u] = (_Float16)T[cv + u][pl2];
        *(half8*)(Bh + (size_t)(p0 + pl2) * C + c0 + cv) = v;
    }
}

// ---------------- D0 GEMM: 256x256 tile, 8-wave, 8-phase counted-vmcnt schedule ----------------
// Schedule (per iteration, tiles t_e=2i in buf0 / t_o=2i+1 in buf1, K-tile = 64 split in 2 kh-halves):
//   ph1: read buf0/kh0 (af x8 + bf0,bf1); stage A-kh0(t_o)->buf1;            bar; lgkm0; 16 MFMA; bar
//   ph2: read bf2,bf3;                    stage B-kh0(t_o); vmcnt(4);        bar; ...
//   ph3: read buf0/kh1;                   stage A-kh1(t_o);                  bar; ...
//   ph4: read bf2,bf3;                    stage B-kh1(t_o); vmcnt(4);        bar; ...
//   ph5-8: same with buf1 compute, stage t_e+2 -> buf0 (skip last iter; ph6 tail wait vmcnt(0)).
// vmcnt(4) is always placed BEFORE the phase barrier so the barrier publishes the staged half to all
// waves before the next phase's dependent ds_reads.  Steady state never drains vmcnt to 0.
// WAR: each buffer region is re-staged >=1 barrier after its last lgkm-drained read (verified per-phase).
// LDS layout per (buf,kh): [row 0..255][4 slots of 8 fp16], slot = logical_quad ^ (row&3)
// (pre-swizzled global source, linear LDS dest -> conflict-free ds_read_b128: 8 lanes per 4-bank slot).
__global__ __launch_bounds__(512, 2) void k_gemm16(const _Float16* __restrict__ Ah,
                                                   const _Float16* __restrict__ Bh,
                                                   _Float16* __restrict__ Eo,
                                                   const float* __restrict__ sqn_part,
                                                   const float* __restrict__ mask,
                                                   float* __restrict__ inv_sn,
                                                   float* __restrict__ msum) {
    __shared__ _Float16 SH[65536];             // 128 KiB: A = [0,32768), B = [32768,65536)
    const int tid = threadIdx.x;
    const int bid = blockIdx.x;
    const int swz = (bid & 7) * 32 + (bid >> 3);   // bijective XCD-chunked swizzle (256 % 8 == 0)
    const int by = swz >> 4, bx = swz & 15;

    // ---- pnorm + msum preamble (16 blocks: by==0) ----
    if (by == 0) {
        float* sqs = (float*)SH;               // 384 floats, aliases staging LDS (resynced below)
        const int b = bx;
        for (int e = tid; e < 384; e += 512) {
            int rr = e >> 6, jw = e & 63;
            int gr = refl(b * 4 - 1 + rr);
            float s = 0.f;
            #pragma unroll
            for (int k = 0; k < 8; ++k) s += sqn_part[(size_t)k * P + gr * 64 + jw];
            sqs[rr * 64 + jw] = s;
        }
        __syncthreads();
        if (tid < 256) {
            int p = b * 256 + tid;
            int li = (tid >> 6) + 1;
            int j = p & 63;
            float s2 = 0.f;
            #pragma unroll
            for (int dh = -1; dh <= 1; ++dh)
                #pragma unroll
                for (int dw = -1; dw <= 1; ++dw)
                    s2 += sqs[(li + dh) * 64 + refl(j + dw)];
            inv_sn[p] = 1.0f / sqrtf(s2);
        }
        if (b == 0) {
            __syncthreads();                   // sqs reads done before red overwrites
            float* red = (float*)SH;
            float s = 0.f;
            for (int e = tid; e < P; e += 512) s += mask[e];
            red[tid] = s;
            __syncthreads();
            for (int t = 256; t > 0; t >>= 1) {
                if (tid < t) red[tid] += red[tid + t];
                __syncthreads();
            }
            if (tid == 0) msum[0] = red[0];
        }
        __syncthreads();                       // preamble LDS use complete before staging
    }

    const int wave = tid >> 6, lane = tid & 63;
    const int wr = wave >> 2, wc = wave & 3;           // 2 M-waves x 4 N-waves
    const int quad = lane >> 4, l15 = lane & 15;
    const int i0 = by * 256, j0 = bx * 256;

    // staging roles: thread covers row r2 (+128), slot sl = tid&3; source pre-swizzled by row&3
    const int r2 = tid >> 2;
    const int gofs = ((tid & 3) ^ (r2 & 3)) * 8;
    const _Float16* pA0 = Ah + (size_t)(i0 + r2) * C + gofs;
    const _Float16* pA1 = pA0 + (size_t)128 * C;
    const _Float16* pB0 = Bh + (size_t)(j0 + r2) * C + gofs;
    const _Float16* pB1 = pB0 + (size_t)128 * C;
    const int stw0 = wave * 512;               // rows wave*16.., linear lane*16B dest
    const int stw1 = 4096 + wave * 512;        // rows 128+wave*16..

    // fragment read offsets (fp16 units within one (buf,kh) region of 8192)
    const int aslot = (quad ^ (l15 & 3)) * 8;
    int aoff[8], boff[4];
    #pragma unroll
    for (int mi = 0; mi < 8; ++mi) aoff[mi] = (wr * 128 + mi * 16 + l15) * 32 + aslot;
    #pragma unroll
    for (int ni = 0; ni < 4; ++ni) boff[ni] = (wc * 64 + ni * 16 + l15) * 32 + aslot;

    f32x4 acc[8][4] = {};
    half8 af[8], bf0, bf1, bf2, bf3;

#define LDSA(b,k) (SH + (b) * 16384 + (k) * 8192)
#define LDSB(b,k) (SH + 32768 + (b) * 16384 + (k) * 8192)
#define STAGE_A(b,k,KC) do { g2l16(pA0 + (KC) + (k) * 32, LDSA(b,k) + stw0); \
                             g2l16(pA1 + (KC) + (k) * 32, LDSA(b,k) + stw1); } while (0)
#define STAGE_B(b,k,KC) do { g2l16(pB0 + (KC) + (k) * 32, LDSB(b,k) + stw0); \
                             g2l16(pB1 + (KC) + (k) * 32, LDSB(b,k) + stw1); } while (0)
#define READ_NP0(b,k) do { _Pragma("unroll") for (int mi = 0; mi < 8; ++mi) \
                               af[mi] = *(const half8*)(LDSA(b,k) + aoff[mi]); \
                           bf0 = *(const half8*)(LDSB(b,k) + boff[0]); \
                           bf1 = *(const half8*)(LDSB(b,k) + boff[1]); } while (0)
#define READ_NP1(b,k) do { bf2 = *(const half8*)(LDSB(b,k) + boff[2]); \
                           bf3 = *(const half8*)(LDSB(b,k) + boff[3]); } while (0)
#define MF8(BF,NI) do { _Pragma("unroll") for (int mi = 0; mi < 8; ++mi) \
    acc[mi][NI] = __builtin_amdgcn_mfma_f32_16x16x32_f16(af[mi], BF, acc[mi][NI], 0, 0, 0); } while (0)
#define WAITV4 asm volatile("s_waitcnt vmcnt(4)" ::: "memory")
#define WAITV0 asm volatile("s_waitcnt vmcnt(0)" ::: "memory")
#define EXEC16(B0,N0,B1,N1) do { \
    __builtin_amdgcn_s_barrier(); \
    asm volatile("s_waitcnt lgkmcnt(0)" ::: "memory"); \
    __builtin_amdgcn_sched_barrier(0); \
    __builtin_amdgcn_s_setprio(1); \
    MF8(B0, N0); MF8(B1, N1); \
    __builtin_amdgcn_s_setprio(0); \
    __builtin_amdgcn_s_barrier(); } while (0)

    // prologue: stage tile0 -> buf0 (order: A-kh0, B-kh0, A-kh1, B-kh1); publish kh0
    STAGE_A(0, 0, 0); STAGE_B(0, 0, 0); STAGE_A(0, 1, 0); STAGE_B(0, 1, 0);
    WAITV4;
    __builtin_amdgcn_s_barrier();

    for (int it = 0; it < 4; ++it) {           // K = 512 = 4 iters x 2 K-tiles x 64
        const int kk = it * 128;
        const bool nl = (it < 3);
        // ---- tile 2it (buf0); stage tile 2it+1 -> buf1 ----
        READ_NP0(0, 0); STAGE_A(1, 0, kk + 64);          EXEC16(bf0, 0, bf1, 1);   // ph1
        READ_NP1(0, 0); STAGE_B(1, 0, kk + 64); WAITV4;  EXEC16(bf2, 2, bf3, 3);   // ph2
        READ_NP0(0, 1); STAGE_A(1, 1, kk + 64);          EXEC16(bf0, 0, bf1, 1);   // ph3
        READ_NP1(0, 1); STAGE_B(1, 1, kk + 64); WAITV4;  EXEC16(bf2, 2, bf3, 3);   // ph4
        // ---- tile 2it+1 (buf1); stage tile 2it+2 -> buf0 (skip on last iter) ----
        READ_NP0(1, 0); if (nl) STAGE_A(0, 0, kk + 128);
        EXEC16(bf0, 0, bf1, 1);                                                    // ph5
        READ_NP1(1, 0); if (nl) { STAGE_B(0, 0, kk + 128); WAITV4; } else { WAITV0; }
        EXEC16(bf2, 2, bf3, 3);                                                    // ph6
        READ_NP0(1, 1); if (nl) STAGE_A(0, 1, kk + 128);
        EXEC16(bf0, 0, bf1, 1);                                                    // ph7
        READ_NP1(1, 1); if (nl) { STAGE_B(0, 1, kk + 128); WAITV4; }
        EXEC16(bf2, 2, bf3, 3);                                                    // ph8
    }

#undef LDSA
#undef LDSB
#undef STAGE_A
#undef STAGE_B
#undef READ_NP0
#undef READ_NP1
#undef MF8
#undef WAITV4
#undef WAITV0
#undef EXEC16

    // epilogue: two 128-row passes; acc -> LDS fp16 (stride 130), w-diagonal 3-sum -> E
    __syncthreads();
    #pragma unroll
    for (int h = 0; h < 2; ++h) {
        if (wr == h) {
            #pragma unroll
            for (int mi = 0; mi < 8; ++mi) {
                const int row = mi * 16 + quad * 4;
                #pragma unroll
                for (int ni = 0; ni < 4; ++ni) {
                    const int col = wc * 64 + ni * 16 + l15;
                    #pragma unroll
                    for (int r = 0; r < 4; ++r)
                        SH[(row + r) * 130 + col] = (_Float16)acc[mi][ni][r];
                }
            }
        }
        __syncthreads();
        {
            const int er  = tid >> 2;              // 0..127 (local row)
            const int c00 = (tid & 3) * 8;
            const int ew  = er & 63;
            const int rm  = (er & 64) | (ew == 0 ? 1 : ew - 1);
            const int rp  = (er & 64) | (ew == 63 ? 62 : ew + 1);
            _Float16* outRow = Eo + (size_t)(i0 + h * 128 + er) * P + j0;
            #pragma unroll
            for (int cc = 0; cc < 256; cc += 32) {
                half8 ev;
                #pragma unroll
                for (int u = 0; u < 8; ++u) {
                    const int c  = c00 + cc + u;
                    const int cw = c & 63;
                    const int cm = (c & ~63) | (cw == 0 ? 1 : cw - 1);
                    const int cp = (c & ~63) | (cw == 63 ? 62 : cw + 1);
                    ev[u] = (_Float16)((float)SH[rm * 130 + cm] + (float)SH[er * 130 + c] + (float)SH[rp * 130 + cp]);
                }
                *(half8*)(outRow + c00 + cc) = ev;
            }
        }
        if (h == 0) __syncthreads();
    }
}

// ---------------- h-diagonal 3-sum + normalize + argmax (r6-verified) ----------------
__global__ __launch_bounds__(256) void k_argmax(const _Float16* __restrict__ E,
                                                const float* __restrict__ inv_sn,
                                                int* __restrict__ idxOut) {
    const int i = blockIdx.x;
    const int ih = i >> 6, iw = i & 63;
    const int wave = threadIdx.x >> 6, l = threadIdx.x & 63, l15 = l & 15;
    size_t rb0 = (size_t)(refl(ih - 1) * 64 + iw) * P;
    size_t rb1 = (size_t)(ih * 64 + iw) * P;
    size_t rb2 = (size_t)(refl(ih + 1) * 64 + iw) * P;

    float best = -1e30f;
    int bidx = 0;
    #pragma unroll
    for (int s = 0; s < 4; ++s) {
        const int j0 = (wave * 4 + s) * 256 + l * 4;
        const int jh = j0 >> 6, jw0 = l15 * 4;
        const int cb0 = ((jh == 0) ? 1 : jh - 1) * 64 + jw0;
        const int cb1 = jh * 64 + jw0;
        const int cb2 = ((jh == 63) ? 62 : jh + 1) * 64 + jw0;
        uint2 u0 = *(const uint2*)(E + rb0 + cb0);
        uint2 u1 = *(const uint2*)(E + rb1 + cb1);
        uint2 u2 = *(const uint2*)(E + rb2 + cb2);
        half2v a0 = __builtin_bit_cast(half2v, u0.x), a1 = __builtin_bit_cast(half2v, u0.y);
        half2v b0 = __builtin_bit_cast(half2v, u1.x), b1 = __builtin_bit_cast(half2v, u1.y);
        half2v c0 = __builtin_bit_cast(half2v, u2.x), c1 = __builtin_bit_cast(half2v, u2.y);
        float f0 = (float)a0[0] + (float)b0[0] + (float)c0[0];
        float f1 = (float)a0[1] + (float)b0[1] + (float)c0[1];
        float f2 = (float)a1[0] + (float)b1[0] + (float)c1[0];
        float f3 = (float)a1[1] + (float)b1[1] + (float)c1[1];
        const float4 is = *(const float4*)(inv_sn + j0);
        float v0 = f0 * is.x, v1 = f1 * is.y, v2 = f2 * is.z, v3 = f3 * is.w;
        if (v0 > best) { best = v0; bidx = j0; }
        if (v1 > best) { best = v1; bidx = j0 + 1; }
        if (v2 > best) { best = v2; bidx = j0 + 2; }
        if (v3 > best) { best = v3; bidx = j0 + 3; }
    }

    __shared__ float bv[256];
    __shared__ int   bi[256];
    bv[threadIdx.x] = best;
    bi[threadIdx.x] = bidx;
    __syncthreads();
    for (int t = 128; t > 0; t >>= 1) {
        if (threadIdx.x < t) {
            float ov = bv[threadIdx.x + t];
            int   oi = bi[threadIdx.x + t];
            if (ov > bv[threadIdx.x] || (ov == bv[threadIdx.x] && oi < bi[threadIdx.x])) {
                bv[threadIdx.x] = ov;
                bi[threadIdx.x] = oi;
            }
        }
        __syncthreads();
    }
    if (threadIdx.x == 0) idxOut[i] = bi[0];
}

// ---------------- build masked fp16 matrices; coalesced row-gather, 256 blocks ----------------
__global__ __launch_bounds__(256) void k_build(const _Float16* __restrict__ Bh,
                                               const float* __restrict__ input,
                                               const float* __restrict__ mask,
                                               const int* __restrict__ idx,
                                               _Float16* __restrict__ fc, _Float16* __restrict__ fg) {
    __shared__ _Float16 G[16][520];
    __shared__ float mk[16];
    const int p0 = blockIdx.x * 16;            // 256 blocks
    const int wave = threadIdx.x >> 6, lane = threadIdx.x & 63;

    // fg: input*mask, 32 flat elements per thread
    {
        int e0 = (blockIdx.x * 256 + threadIdx.x) * 32;
        #pragma unroll
        for (int v = 0; v < 4; ++v) {
            int e = e0 + v * 8;
            int pp = e & (P - 1);
            half8 vg;
            #pragma unroll
            for (int u = 0; u < 8; ++u)
                vg[u] = (_Float16)(input[e + u] * mask[pp + u]);
            *(half8*)(fg + e) = vg;
        }
    }

    if (threadIdx.x < 16) mk[threadIdx.x] = mask[p0 + threadIdx.x];

    // gather 16 style rows (fp16, from Bh[p][c]) into LDS — fully coalesced
    #pragma unroll
    for (int r = 0; r < 4; ++r) {
        int pp = wave * 4 + r;
        int row = idx[p0 + pp];                // wave-uniform
        *(half8*)(&G[pp][lane * 8]) = *(const half8*)(Bh + (size_t)row * C + lane * 8);
    }
    __syncthreads();

    // transpose + mask: thread handles channel c and c+256; 32B store per c
    #pragma unroll
    for (int h = 0; h < 2; ++h) {
        int c = h * 256 + threadIdx.x;
        half8 o[2];
        #pragma unroll
        for (int q = 0; q < 2; ++q)
            #pragma unroll
            for (int u = 0; u < 8; ++u) {
                int p = q * 8 + u;
                o[q][u] = (_Float16)((float)G[p][c] * mk[p]);
            }
        _Float16* dst = fc + (size_t)c * P + p0;
        *(half8*)(dst)     = o[0];
        *(half8*)(dst + 8) = o[1];
    }
}

// ---------------- gram diff partials, lower-triangle tiles only (G, T symmetric) ----------------
__device__ __constant__ int TBX[10] = {0, 0, 1, 0, 1, 2, 0, 1, 2, 3};
__device__ __constant__ int TBY[10] = {0, 1, 1, 2, 2, 2, 3, 3, 3, 3};

__global__ __launch_bounds__(256) void k_gram(const _Float16* __restrict__ fg,
                                              const _Float16* __restrict__ fc,
                                              float* __restrict__ part) {
    const int t = blockIdx.x, z = blockIdx.z;
    const int p0 = z * 256;
    const int wave = threadIdx.x >> 6, lane = threadIdx.x & 63;
    const int wr = wave >> 1, wc = wave & 1, quad = lane >> 4, l15 = lane & 15;
    const int a0 = TBY[t] * 128 + wr * 64, b0 = TBX[t] * 128 + wc * 64;

    f32x4 accg[4][4] = {};
    f32x4 accc[4][4] = {};
    for (int ks = 0; ks < 256; ks += 32) {
        int kbase = p0 + ks + quad * 8;
        half8 af[4], bf[4];
        #pragma unroll
        for (int mi = 0; mi < 4; ++mi) af[mi] = *(const half8*)(fg + (size_t)(a0 + mi * 16 + l15) * P + kbase);
        #pragma unroll
        for (int ni = 0; ni < 4; ++ni) bf[ni] = *(const half8*)(fg + (size_t)(b0 + ni * 16 + l15) * P + kbase);
        #pragma unroll
        for (int mi = 0; mi < 4; ++mi)
            #pragma unroll
            for (int ni = 0; ni < 4; ++ni)
                accg[mi][ni] = __builtin_amdgcn_mfma_f32_16x16x32_f16(af[mi], bf[ni], accg[mi][ni], 0, 0, 0);
        #pragma unroll
        for (int mi = 0; mi < 4; ++mi) af[mi] = *(const half8*)(fc + (size_t)(a0 + mi * 16 + l15) * P + kbase);
        #pragma unroll
        for (int ni = 0; ni < 4; ++ni) bf[ni] = *(const half8*)(fc + (size_t)(b0 + ni * 16 + l15) * P + kbase);
        #pragma unroll
        for (int mi = 0; mi < 4; ++mi)
            #pragma unroll
            for (int ni = 0; ni < 4; ++ni)
                accc[mi][ni] = __builtin_amdgcn_mfma_f32_16x16x32_f16(af[mi], bf[ni], accc[mi][ni], 0, 0, 0);
    }
    float* dst = part + (size_t)(z * 10 + t) * 16384;
    #pragma unroll
    for (int mi = 0; mi < 4; ++mi)
        #pragma unroll
        for (int ni = 0; ni < 4; ++ni)
            #pragma unroll
            for (int r = 0; r < 4; ++r)
                dst[(wr * 64 + mi * 16 + quad * 4 + r) * 128 + wc * 64 + ni * 16 + l15]
                    = accg[mi][ni][r] - accc[mi][ni][r];
}

// ---------------- loss partials: w[t]*(sum_z part)^2, plain store ----------------
__global__ void k_loss(const float* __restrict__ part, float* __restrict__ lsum) {
    int e = blockIdx.x * 256 + threadIdx.x;
    int t = e >> 14, loc = e & 16383;
    float d = 0.f;
    #pragma unroll
    for (int z = 0; z < 16; ++z) d += part[(size_t)(z * 10 + t) * 16384 + loc];
    float w = (TBX[t] == TBY[t]) ? 1.0f : 2.0f;
    __shared__ float red[256];
    red[threadIdx.x] = d * d * w;
    __syncthreads();
    for (int s = 128; s > 0; s >>= 1) {
        if (threadIdx.x < s) red[threadIdx.x] += red[threadIdx.x + s];
        __syncthreads();
    }
    if (threadIdx.x == 0) lsum[blockIdx.x] = red[0];
}

__global__ void k_final(const float* __restrict__ lsum, const float* __restrict__ msum,
                        float* __restrict__ out) {
    __shared__ float red[256];
    float s = 0.f;
    for (int e = threadIdx.x; e < 640; e += 256) s += lsum[e];
    red[threadIdx.x] = s;
    __syncthreads();
    for (int t = 128; t > 0; t >>= 1) {
        if (threadIdx.x < t) red[threadIdx.x] += red[threadIdx.x + t];
        __syncthreads();
    }
    if (threadIdx.x == 0) {
        float m = msum[0];
        out[0] = red[0] * 100.0f / (m * m * 262144.0f);
    }
}

extern "C" void kernel_launch(void* const* d_in, const int* in_sizes, int n_in,
                              void* d_out, int out_size, void* d_ws, size_t ws_size,
                              hipStream_t stream) {
    (void)in_sizes; (void)n_in; (void)out_size; (void)ws_size;
    const float* content = (const float*)d_in[0];
    const float* style   = (const float*)d_in[1];
    const float* input   = (const float*)d_in[2];
    const float* mask    = (const float*)d_in[3];

    char* ws = (char*)d_ws;
    _Float16* Eb   = (_Float16*)ws;                        // 32 MB (dead after k_argmax)
    float*    part = (float*)ws;                           // 10.5 MB (overlays Eb)
    _Float16* Ah   = (_Float16*)(ws + (32u << 20));        // 4 MB
    _Float16* Bh   = (_Float16*)(ws + (36u << 20));        // 4 MB
    _Float16* fg_h = (_Float16*)(ws + (40u << 20));        // 4 MB
    _Float16* fc_h = (_Float16*)(ws + (44u << 20));        // 4 MB
    float*    small = (float*)(ws + (48u << 20));
    float* sqn_part = small;               // 8*4096
    float* inv_sn   = small + 32768;       // 4096
    float* msum     = small + 36864;
    float* lsum     = small + 36992;       // 640
    int*   idx      = (int*)(small + 37888);
    float* out = (float*)d_out;

    k_prep  <<<512, 256, 0, stream>>>(content, style, Ah, Bh, sqn_part);
    k_gemm16<<<256, 512, 0, stream>>>(Ah, Bh, Eb, sqn_part, mask, inv_sn, msum);
    k_argmax<<<4096, 256, 0, stream>>>(Eb, inv_sn, idx);
    k_build <<<256, 256, 0, stream>>>(Bh, input, mask, idx, fc_h, fg_h);
    k_gram  <<<dim3(10, 1, 16), 256, 0, stream>>>(fg_h, fc_h, part);
    k_loss  <<<640, 256, 0, stream>>>(part, lsum);
    k_final <<<1, 256, 0, stream>>>(lsum, msum, out);
}